// Round 4
// baseline (191.226 us; speedup 1.0000x reference)
//
#include <hip/hip_runtime.h>
#include <hip/hip_bf16.h>
#include <stdint.h>

#define CAP 32

static constexpr int BATCH = 2048;
static constexpr int D0 = 4096;
static constexpr int D1 = 8192;
static constexpr int D2 = 8192;
static constexpr int D3 = 4096;
static constexpr int ROWS_PAD = 8192;

static constexpr size_t PREFIX_BYTES = 16u << 20;

// ---------------- ws layout (bytes, 256-aligned) ----------------
static constexpr size_t OFF_DET   = 0;                               // 2 u32 (256B slot)
static constexpr size_t OFF_REFD2 = 256;                             // 8192 int
static constexpr size_t ZERO_BYTES= OFF_REFD2 + (size_t)ROWS_PAD*4;  // 33 KB: det+refd2
static constexpr size_t OFF_CNT   = ZERO_BYTES;                      // 3*8192 int (fully written, no zero)
static constexpr size_t OFF_TB    = OFF_CNT + 3ull*ROWS_PAD*4;       // 2*8192 float
static constexpr size_t OFF_RK    = OFF_TB + 2ull*ROWS_PAD*4;        // 3*8192*CAP int
static constexpr size_t OFF_RW    = OFF_RK + 3ull*ROWS_PAD*CAP*4;
static constexpr size_t OFF_XT    = OFF_RW + 3ull*ROWS_PAD*CAP*4;    // xT [4096][2048]
static constexpr size_t OFF_H1    = OFF_XT + 33554432ull;            // h1T [8192][2048]
static constexpr size_t OFF_H2    = OFF_H1 + 67108864ull;            // h2T [8192][2048]
static constexpr size_t WS_BIG    = OFF_H2 + 67108864ull;            // ~174.3 MB

// ---------------------------------------------------------------------------
// Mask dtype detection (byte-pattern statistics over 16MB prefix of m1).
// ---------------------------------------------------------------------------
__global__ void detect_kernel(const uint8_t* __restrict__ m, unsigned* __restrict__ det) {
    const uint4* p = (const uint4*)m;
    const int n16 = (int)(PREFIX_BYTES / 16);
    unsigned c123 = 0, c4 = 0;
    for (int i = blockIdx.x * blockDim.x + threadIdx.x; i < n16; i += gridDim.x * blockDim.x) {
        uint4 q = p[i];
        if ((q.x | q.y | q.z | q.w) == 0u) continue;
        unsigned w[4] = {q.x, q.y, q.z, q.w};
        for (int t = 0; t < 4; ++t) {
            unsigned v = w[t];
            if (!v) continue;
            for (int bb = 0; bb < 4; ++bb) {
                if ((v >> (8 * bb)) & 0xFFu) {
                    int posmod8 = ((t * 4 + bb) & 7);
                    if (posmod8 & 3) c123++;
                    else if (posmod8 == 4) c4++;
                }
            }
        }
    }
    if (c123) atomicAdd(&det[0], c123);
    if (c4)   atomicAdd(&det[1], c4);
}

__device__ __forceinline__ int decide_mode(const unsigned* det) {
    unsigned c123 = det[0], c4 = det[1];
    if (c123 > 1050u) return 0;          // 1-byte elements
    if (c123 > 400u)  return 1;          // float32 / int32 (nonzero test)
    return (c4 > 80u) ? 1 : 2;           // int32 vs int64
}

// ---------------------------------------------------------------------------
// Row extraction body: scan one mask row, emit sorted (col, w) list.
// Optionally mark refd_prev[col] (consumer-side liveness for the feeding layer).
// ---------------------------------------------------------------------------
__device__ __forceinline__ void extract_row(const void* mask, const float* W,
                                            int fan_in, int row, int mode,
                                            int* cnt, int* rowk, float* roww,
                                            int* refd_prev) {
    __shared__ int lcnt;
    __shared__ int lk[CAP];
    if (threadIdx.x == 0) lcnt = 0;
    __syncthreads();

    auto push = [&](int k) {
        int pos = atomicAdd(&lcnt, 1);
        if (pos < CAP) lk[pos] = k;
    };

    if (mode == 0) {
        const uint4* p = (const uint4*)((const uint8_t*)mask + (size_t)row * fan_in);
        const int nch = fan_in / 16;
        for (int ci = threadIdx.x; ci < nch; ci += blockDim.x) {
            uint4 q = p[ci];
            if ((q.x | q.y | q.z | q.w) == 0u) continue;
            unsigned w[4] = {q.x, q.y, q.z, q.w};
            int base = ci * 16;
            for (int t = 0; t < 4; ++t) {
                unsigned v = w[t];
                if (!v) continue;
                for (int bb = 0; bb < 4; ++bb)
                    if ((v >> (8 * bb)) & 0xFFu) push(base + t * 4 + bb);
            }
        }
    } else if (mode == 1) {
        const int4* p = (const int4*)((const int*)mask + (size_t)row * fan_in);
        const int nch = fan_in / 4;
        for (int ci = threadIdx.x; ci < nch; ci += blockDim.x) {
            int4 q = p[ci];
            if ((q.x | q.y | q.z | q.w) == 0) continue;
            int base = ci * 4;
            if (q.x) push(base + 0);
            if (q.y) push(base + 1);
            if (q.z) push(base + 2);
            if (q.w) push(base + 3);
        }
    } else {
        const longlong2* p = (const longlong2*)((const long long*)mask + (size_t)row * fan_in);
        const int nch = fan_in / 2;
        for (int ci = threadIdx.x; ci < nch; ci += blockDim.x) {
            longlong2 q = p[ci];
            if ((q.x | q.y) == 0ll) continue;
            int base = ci * 2;
            if (q.x) push(base + 0);
            if (q.y) push(base + 1);
        }
    }
    __syncthreads();

    if (threadIdx.x == 0) {
        int c = lcnt;
        if (c > CAP) c = CAP;
        for (int a = 1; a < c; ++a) {            // sort -> deterministic order
            int v = lk[a];
            int b = a - 1;
            while (b >= 0 && lk[b] > v) { lk[b + 1] = lk[b]; --b; }
            lk[b + 1] = v;
        }
        cnt[row] = c;
        for (int a = 0; a < c; ++a) {
            int k = lk[a];
            rowk[(size_t)row * CAP + a] = k;
            roww[(size_t)row * CAP + a] = W[(size_t)row * fan_in + k];
            if (refd_prev) atomicOr(&refd_prev[k], 1);
        }
    }
}

// ---------------------------------------------------------------------------
// Sparse layer row body, batch-major. 256 threads, two float4 per thread.
// ---------------------------------------------------------------------------
template<bool HAS_TB, bool USE_REFD>
__device__ __forceinline__ void layer_row(int j, const float* __restrict__ inT,
                                          const float* __restrict__ bias,
                                          const float* __restrict__ tb_in,
                                          const int* __restrict__ cnt_in,
                                          const int* __restrict__ cnt,
                                          const int* __restrict__ rowk,
                                          const float* __restrict__ roww,
                                          const int* __restrict__ refd,
                                          float* __restrict__ outT) {
    const int c = cnt[j];
    if (c == 0) return;
    if (USE_REFD) { if (refd[j] == 0) return; }

    const int*   kk = rowk + (size_t)j * CAP;
    const float* ww = roww + (size_t)j * CAP;

    float base = bias[j];
    if (HAS_TB) {
        for (int e = 0; e < c; ++e) {
            int k = kk[e];
            if (cnt_in[k] == 0) base += ww[e] * tb_in[k];   // inactive input: constant
        }
    }

    const int l = threadIdx.x;
    float4 acc0 = make_float4(base, base, base, base);
    float4 acc1 = acc0;

    for (int e = 0; e < c; ++e) {
        int k = kk[e];
        if (HAS_TB && cnt_in[k] == 0) continue;
        const float w = ww[e];
        const float* row = inT + (size_t)k * BATCH;
        float4 v0 = *(const float4*)(row + l * 4);
        float4 v1 = *(const float4*)(row + 1024 + l * 4);
        acc0.x += w * v0.x; acc0.y += w * v0.y; acc0.z += w * v0.z; acc0.w += w * v0.w;
        acc1.x += w * v1.x; acc1.y += w * v1.y; acc1.z += w * v1.z; acc1.w += w * v1.w;
    }

    acc0.x = tanhf(acc0.x); acc0.y = tanhf(acc0.y);
    acc0.z = tanhf(acc0.z); acc0.w = tanhf(acc0.w);
    acc1.x = tanhf(acc1.x); acc1.y = tanhf(acc1.y);
    acc1.z = tanhf(acc1.z); acc1.w = tanhf(acc1.w);

    float* orow = outT + (size_t)j * BATCH;
    *(float4*)(orow + l * 4) = acc0;
    *(float4*)(orow + 1024 + l * 4) = acc1;
}

// ---------------------------------------------------------------------------
// K1: extract m1  ∥  full x-transpose  ∥  tanh-bias tables. One launch.
// blocks: [0,8192) m1 rows; [8192,16384) transpose tiles; [16384,16448) tb.
// ---------------------------------------------------------------------------
__global__ void k1_kernel(const void* __restrict__ m1, const float* __restrict__ W1,
                          const float* __restrict__ x,
                          const float* __restrict__ b1, const float* __restrict__ b2,
                          const unsigned* __restrict__ det,
                          int* __restrict__ cnt1, int* __restrict__ rk1, float* __restrict__ rw1,
                          float* __restrict__ tb1, float* __restrict__ tb2,
                          float* __restrict__ xT) {
    const int bid = blockIdx.x;
    if (bid < D1) {
        extract_row(m1, W1, D0, bid, decide_mode(det), cnt1, rk1, rw1, nullptr);
    } else if (bid < D1 + (D0 / 32) * (BATCH / 32)) {
        __shared__ float tile[32][33];
        const int t = bid - D1;
        const int cx = t & 127;          // D0/32 = 128 col tiles
        const int ry = t >> 7;           // BATCH/32 = 64 row tiles
        const int tx = threadIdx.x & 31, ty = threadIdx.x >> 5;
        const int c0 = cx * 32, r0 = ry * 32;
        for (int i = ty; i < 32; i += 8)
            tile[i][tx] = x[(size_t)(r0 + i) * D0 + c0 + tx];
        __syncthreads();
        for (int i = ty; i < 32; i += 8)
            xT[(size_t)(c0 + i) * BATCH + r0 + tx] = tile[tx][i];
    } else {
        int tid = (bid - D1 - (D0 / 32) * (BATCH / 32)) * 256 + threadIdx.x;
        if (tid < D1) tb1[tid] = tanhf(b1[tid]);
        else if (tid < D1 + D2) tb2[tid - D1] = tanhf(b2[tid - D1]);
    }
}

// ---------------------------------------------------------------------------
// K2: extract m2+m3 (the 402 MB long pole)  ∥  layer-1 compute (depends only
// on K1). m3 extraction also marks refd2 for layer-2's row filter.
// blocks: [0,8192) m2; [8192,12288) m3; [12288,20480) layer-1 rows.
// ---------------------------------------------------------------------------
__global__ void k2_kernel(const void* __restrict__ m2, const float* __restrict__ W2,
                          const void* __restrict__ m3, const float* __restrict__ W3,
                          const unsigned* __restrict__ det,
                          int* __restrict__ cnt2, int* __restrict__ rk2, float* __restrict__ rw2,
                          int* __restrict__ cnt3, int* __restrict__ rk3, float* __restrict__ rw3,
                          int* __restrict__ refd2,
                          const float* __restrict__ xT, const float* __restrict__ b1,
                          const int* __restrict__ cnt1, const int* __restrict__ rk1,
                          const float* __restrict__ rw1,
                          float* __restrict__ h1T) {
    const int bid = blockIdx.x;
    if (bid < D2) {
        extract_row(m2, W2, D1, bid, decide_mode(det), cnt2, rk2, rw2, nullptr);
    } else if (bid < D2 + D3) {
        extract_row(m3, W3, D2, bid - D2, decide_mode(det), cnt3, rk3, rw3, refd2);
    } else {
        layer_row<false, false>(bid - D2 - D3, xT, b1, nullptr, nullptr,
                                cnt1, rk1, rw1, nullptr, h1T);
    }
}

// K3: layer-2 (refd2-filtered).
__global__ void layer2_kernel(const float* __restrict__ h1T, const float* __restrict__ b2,
                              const float* __restrict__ tb1, const int* __restrict__ cnt1,
                              const int* __restrict__ cnt2, const int* __restrict__ rk2,
                              const float* __restrict__ rw2, const int* __restrict__ refd2,
                              float* __restrict__ h2T) {
    layer_row<true, true>(blockIdx.x, h1T, b2, tb1, cnt1, cnt2, rk2, rw2, refd2, h2T);
}

// ---------------------------------------------------------------------------
// K4: fused layer-3 + output transpose. Block (32,8): 32j x 32b tile,
// coalesced out[b][j] store via LDS transpose.
// ---------------------------------------------------------------------------
__global__ void l3t_kernel(const float* __restrict__ h2T,
                           const float* __restrict__ b3, const float* __restrict__ tb2,
                           const int* __restrict__ cnt2,
                           const int* __restrict__ c3, const int* __restrict__ k3,
                           const float* __restrict__ w3,
                           float* __restrict__ out) {
    __shared__ float tile[32][33];
    const int j0 = blockIdx.x * 32, b0 = blockIdx.y * 32;
    const int tx = threadIdx.x, ty = threadIdx.y;

    for (int s = 0; s < 4; ++s) {
        int jl = ty + 8 * s;
        int j = j0 + jl;
        float acc = b3[j];
        int c = c3[j];
        const int* kk = k3 + (size_t)j * CAP;
        const float* ww = w3 + (size_t)j * CAP;
        for (int e = 0; e < c; ++e) {
            int k = kk[e];
            float w = ww[e];
            acc += w * (cnt2[k] ? h2T[(size_t)k * BATCH + b0 + tx] : tb2[k]);
        }
        tile[jl][tx] = acc;
    }
    __syncthreads();
    for (int s = 0; s < 4; ++s) {
        int bl = ty + 8 * s;
        out[(size_t)(b0 + bl) * D3 + j0 + tx] = tile[tx][bl];
    }
}

// ---------------------------------------------------------------------------
// Fallback path (ws too small): standalone extracts + chained evaluation.
// ---------------------------------------------------------------------------
__global__ void extract_only_kernel(const void* __restrict__ mask, const float* __restrict__ W,
                                    int fan_in,
                                    int* __restrict__ cnt, int* __restrict__ rowk,
                                    float* __restrict__ roww, const unsigned* __restrict__ det) {
    extract_row(mask, W, fan_in, blockIdx.x, decide_mode(det), cnt, rowk, roww, nullptr);
}

__global__ void out_kernel(const float* __restrict__ x,
                           const float* __restrict__ b1, const float* __restrict__ b2,
                           const float* __restrict__ b3,
                           const int* __restrict__ c1, const int* __restrict__ k1,
                           const float* __restrict__ w1,
                           const int* __restrict__ c2, const int* __restrict__ k2,
                           const float* __restrict__ w2,
                           const int* __restrict__ c3, const int* __restrict__ k3,
                           const float* __restrict__ w3,
                           float* __restrict__ out) {
    int idx = blockIdx.x * blockDim.x + threadIdx.x;
    if (idx >= BATCH * D3) return;
    int b = idx >> 12;
    int j = idx & 4095;

    float acc = b3[j];
    int c = c3[j];
    for (int e = 0; e < c; ++e) {
        int kk2 = k3[(size_t)j * CAP + e];
        float a2 = b2[kk2];
        int cc2 = c2[kk2];
        for (int e2 = 0; e2 < cc2; ++e2) {
            int kk1 = k2[(size_t)kk2 * CAP + e2];
            float a1 = b1[kk1];
            int cc1 = c1[kk1];
            for (int e1 = 0; e1 < cc1; ++e1) {
                int kk0 = k1[(size_t)kk1 * CAP + e1];
                a1 += w1[(size_t)kk1 * CAP + e1] * x[(size_t)b * D0 + kk0];
            }
            a2 += w2[(size_t)kk2 * CAP + e2] * tanhf(a1);
        }
        acc += w3[(size_t)j * CAP + e] * tanhf(a2);
    }
    out[idx] = acc;
}

extern "C" void kernel_launch(void* const* d_in, const int* in_sizes, int n_in,
                              void* d_out, int out_size, void* d_ws, size_t ws_size,
                              hipStream_t stream) {
    const float* x  = (const float*)d_in[0];
    const float* W1 = (const float*)d_in[1];
    const float* b1 = (const float*)d_in[2];
    const void*  m1 = d_in[3];
    const float* W2 = (const float*)d_in[4];
    const float* b2 = (const float*)d_in[5];
    const void*  m2 = d_in[6];
    const float* W3 = (const float*)d_in[7];
    const float* b3 = (const float*)d_in[8];
    const void*  m3 = d_in[9];

    uint8_t* ws = (uint8_t*)d_ws;
    unsigned* det = (unsigned*)(ws + OFF_DET);
    int* refd2 = (int*)(ws + OFF_REFD2);
    int* cnt1 = (int*)(ws + OFF_CNT);
    int* cnt2 = cnt1 + ROWS_PAD;
    int* cnt3 = cnt2 + ROWS_PAD;
    float* tb1 = (float*)(ws + OFF_TB);
    float* tb2 = tb1 + ROWS_PAD;
    int* rk1 = (int*)(ws + OFF_RK);
    int* rk2 = rk1 + (size_t)ROWS_PAD * CAP;
    int* rk3 = rk2 + (size_t)ROWS_PAD * CAP;
    float* rw1 = (float*)(ws + OFF_RW);
    float* rw2 = rw1 + (size_t)ROWS_PAD * CAP;
    float* rw3 = rw2 + (size_t)ROWS_PAD * CAP;
    float* xT  = (float*)(ws + OFF_XT);
    float* h1T = (float*)(ws + OFF_H1);
    float* h2T = (float*)(ws + OFF_H2);

    hipMemsetAsync(ws, 0, ZERO_BYTES, stream);
    detect_kernel<<<1024, 256, 0, stream>>>((const uint8_t*)m1, det);

    if (ws_size >= WS_BIG) {
        const int K1_BLOCKS = D1 + (D0 / 32) * (BATCH / 32) + (D1 + D2) / 256;  // 16448
        k1_kernel<<<K1_BLOCKS, 256, 0, stream>>>(
            m1, W1, x, b1, b2, det, cnt1, rk1, rw1, tb1, tb2, xT);

        const int K2_BLOCKS = D2 + D3 + D1;                                     // 20480
        k2_kernel<<<K2_BLOCKS, 256, 0, stream>>>(
            m2, W2, m3, W3, det,
            cnt2, rk2, rw2, cnt3, rk3, rw3, refd2,
            xT, b1, cnt1, rk1, rw1, h1T);

        layer2_kernel<<<D2, 256, 0, stream>>>(
            h1T, b2, tb1, cnt1, cnt2, rk2, rw2, refd2, h2T);

        l3t_kernel<<<dim3(D3 / 32, BATCH / 32), dim3(32, 8), 0, stream>>>(
            h2T, b3, tb2, cnt2, cnt3, rk3, rw3, (float*)d_out);
    } else {
        extract_only_kernel<<<D1, 256, 0, stream>>>(m1, W1, D0, cnt1, rk1, rw1, det);
        extract_only_kernel<<<D2, 256, 0, stream>>>(m2, W2, D1, cnt2, rk2, rw2, det);
        extract_only_kernel<<<D3, 256, 0, stream>>>(m3, W3, D2, cnt3, rk3, rw3, det);
        out_kernel<<<(BATCH * D3 + 255) / 256, 256, 0, stream>>>(
            x, b1, b2, b3,
            cnt1, rk1, rw1,
            cnt2, rk2, rw2,
            cnt3, rk3, rw3,
            (float*)d_out);
    }
}